// Round 17
// baseline (68.690 us; speedup 1.0000x reference)
//
#include <hip/hip_runtime.h>

#define NJ   16
#define DM   128
#define NH   8
#define PPB  128        // positions per block (owned contiguously)
#define NW_C 4          // compute waves (waves 0-3); waves 4-7 are store waves
#define ROUNDS (PPB / NW_C)   // 32
#define CL   0.36067376022224085f   // 0.25 * log2(e)

typedef __attribute__((ext_vector_type(8))) short bf16x8;
typedef __attribute__((ext_vector_type(4))) float f32x4;
typedef __attribute__((ext_vector_type(2))) float f32x2;

// Kinematic adjacency (compile-time constant of the reference), UNscaled.
__constant__ float c_adj[NJ * NJ] = {
    1,1,0,0, 1,0,0,1, 0,0,1,0, 0,1,0,0,
    1,1,1,0, 0,0,0,0, 0,0,0,0, 0,0,0,0,
    0,1,1,1, 0,0,0,0, 0,0,0,0, 0,0,0,0,
    0,0,1,1, 0,0,0,0, 0,0,0,0, 0,0,0,0,
    1,0,0,0, 1,1,0,0.8f, 0,0,0,0, 0,0,0,0,
    0,0,0,0, 1,1,1,0, 0.8f,0,0,0, 0,0,0,0,
    0,0,0,0, 0,1,1,0, 0,0.8f,0,0, 0,0,0,0,
    1,0,0,0, 0.8f,0,0,1, 1,0,0,0, 0,0,0,0,
    0,0,0,0, 0,0.8f,0,1, 1,1,0,0, 0,0,0,0,
    0,0,0,0, 0,0,0.8f,0, 1,1,0,0, 0,0,0,0,
    1,0,0,0, 0,0,0,0, 0,0,1,1, 0,0.8f,0,0,
    0,0,0,0, 0,0,0,0, 0,0,1,1, 1,0,0.8f,0,
    0,0,0,0, 0,0,0,0, 0,0,0,1, 1,0,0,0.8f,
    1,0,0,0, 0,0,0,0, 0,0,0.8f,0, 0,1,1,0,
    0,0,0,0, 0,0,0,0, 0,0,0,0.8f, 0,1,1,1,
    0,0,0,0, 0,0,0,0, 0,0,0,0, 0.8f,0,1,1
};

// ws layout (32-bit words):
//   [0,128)     bp[128] fp32        : bv @ Wo + bo
//   [128,256)   pack[8][16] fp32    : per head: M*CL(9), a*CL(3), c*CL(3), d*CL(1)
//   [256,2304)  Gfrag[8][64][4] u32 : bf16x2-packed fragments, k = 4h+r (r==3 -> 0)
#define WS_BP_W   0
#define WS_PACK_W 128
#define WS_GF_W   256

__device__ __forceinline__ unsigned short f2bf(float f) {
    union { float f; unsigned u; } v; v.f = f;
    unsigned u = v.u;
    u += 0x7FFFu + ((u >> 16) & 1u);          // RNE
    return (unsigned short)(u >> 16);
}
__device__ __forceinline__ unsigned pack2bf(float lo, float hi) {
    return (unsigned)f2bf(lo) | ((unsigned)f2bf(hi) << 16);
}

__global__ __launch_bounds__(256) void skel_setup_kernel(
    const float* __restrict__ Wq, const float* __restrict__ bq,
    const float* __restrict__ Wk, const float* __restrict__ bk,
    const float* __restrict__ Wv, const float* __restrict__ bv,
    const float* __restrict__ Wo, const float* __restrict__ bo,
    unsigned* __restrict__ wsu)
{
    const int b = blockIdx.x, t = threadIdx.x;
    float* wsf = (float*)wsu;

    if (b < 8) {
        // One packed u32 (2 bf16, k-pair) of Gfrag per thread.
        const int idx = b * 256 + t;          // 0..2047
        const int ctl = idx >> 2, i = idx & 3;
        const int ct = ctl >> 6, l = ctl & 63;
        const int n  = ct * 16 + (l & 15);
        const int kb = (l >> 4) * 8;
        float v[2];
#pragma unroll
        for (int s = 0; s < 2; ++s) {
            const int k = kb + 2 * i + s;
            const int h = k >> 2, r = k & 3;
            float acc = 0.f;
            if (r < 3) {
#pragma unroll
                for (int dh = 0; dh < 16; ++dh)
                    acc += Wv[r * DM + h * 16 + dh] * Wo[(h * 16 + dh) * DM + n];
            }
            v[s] = acc;
        }
        wsu[WS_GF_W + idx] = pack2bf(v[0], v[1]);
        return;
    }
    // block 8: bp and per-head packs (pre-scaled by CL)
    if (t < 128) {
        const int n = t;
        float bv_ = bo[n];
        for (int d = 0; d < DM; ++d) bv_ += bv[d] * Wo[d * DM + n];
        wsf[WS_BP_W + n] = bv_;
    } else if (t < 128 + NH) {
        const int h = t - 128;
        float* o = &wsf[WS_PACK_W + h * 16];
#pragma unroll
        for (int r = 0; r < 3; ++r)
#pragma unroll
            for (int c = 0; c < 3; ++c) {
                float acc = 0.f;
#pragma unroll
                for (int dh = 0; dh < 16; ++dh)
                    acc += Wq[r * DM + h * 16 + dh] * Wk[c * DM + h * 16 + dh];
                o[r * 3 + c] = acc * CL;
            }
#pragma unroll
        for (int r = 0; r < 3; ++r) {
            float aa = 0.f, cc = 0.f;
#pragma unroll
            for (int dh = 0; dh < 16; ++dh) {
                aa += Wq[r * DM + h * 16 + dh] * bk[h * 16 + dh];
                cc += Wk[r * DM + h * 16 + dh] * bq[h * 16 + dh];
            }
            o[9 + r]  = aa * CL;
            o[12 + r] = cc * CL;
        }
        float dd = 0.f;
#pragma unroll
        for (int dh = 0; dh < 16; ++dh) dd += bq[h * 16 + dh] * bk[h * 16 + dh];
        o[15] = dd * CL;
    }
}

__global__ __launch_bounds__(512) void skel_main_kernel(
    const float* __restrict__ x,
    const unsigned* __restrict__ wsu,
    float* __restrict__ out,
    int npos)
{
    const int t = threadIdx.x;
    const int wv = t >> 6, l = t & 63;
    const float* wsf = (const float*)wsu;
    const long base = (long)blockIdx.x * PPB;

    __shared__ __align__(16) float    sx4[PPB][NJ][4];        // 32 KB ([3] unused)
    __shared__ float                  sc[128];
    __shared__ __align__(16) float    sbp[128];
    __shared__ __align__(16) unsigned sxb[NW_C][NJ * 20];     // 5 KB exchange
    __shared__ __align__(16) float    sout[2][NW_C][NJ * DM]; // 64 KB dbuf handoff

    // ---- prologue: stage x for all PPB positions + constants -----------
    {
        const long lim = (long)npos * 48;
        for (int i = t; i < PPB * 48; i += 512) {
            const long gi = base * 48 + i;
            const int e = i % 48;
            sx4[i / 48][e / 3][e % 3] = (gi < lim) ? x[gi] : 0.f;
        }
    }
    if (t < 128)      sc[t]        = wsf[WS_PACK_W + t];
    else if (t < 256) sbp[t - 128] = wsf[WS_BP_W + (t - 128)];

    // G fragments to registers (global read, no LDS dependency)
    bf16x8 ga[8];
#pragma unroll
    for (int ct = 0; ct < 8; ++ct)
        ga[ct] = *(const bf16x8*)&wsu[WS_GF_W + (ct * 64 + l) * 4];
    __syncthreads();

    const int h  = l >> 3, j0 = l & 7;
    const int jB = l & 15, lkB = l >> 4;

    // compute-wave constants
    float m[16];
    f32x2 adjp[NJ];
    if (wv < NW_C) {
#pragma unroll
        for (int i = 0; i < 16; ++i) m[i] = sc[h * 16 + i];
#pragma unroll
        for (int k = 0; k < NJ; ++k) {
            adjp[k].x = c_adj[j0 * NJ + k] * CL;
            adjp[k].y = c_adj[(j0 + 8) * NJ + k] * CL;
        }
    }

    for (int r = 0; r <= ROUNDS; ++r) {
        if (wv < NW_C) {
            // ================= COMPUTE WAVE =================
            if (r < ROUNDS) {
                const int p = r * NW_C + wv;
                if (base + p < npos) {
                    const f32x4 xa = *(const f32x4*)&sx4[p][j0];
                    const f32x4 xb = *(const f32x4*)&sx4[p][j0 + 8];
                    const f32x2 px = { xa.x, xb.x };
                    const f32x2 py = { xa.y, xb.y };
                    const f32x2 pz = { xa.z, xb.z };

                    const f32x2 y0 = m[0]*px + m[3]*py + m[6]*pz + m[12];
                    const f32x2 y1 = m[1]*px + m[4]*py + m[7]*pz + m[13];
                    const f32x2 y2 = m[2]*px + m[5]*py + m[8]*pz + m[14];
                    const f32x2 uu = m[9]*px + m[10]*py + m[11]*pz + m[15];

                    f32x2 sum = { 0.f, 0.f };
                    f32x2 A0 = { 0.f, 0.f }, A1 = { 0.f, 0.f }, A2 = { 0.f, 0.f };
#pragma unroll
                    for (int k = 0; k < NJ; ++k) {
                        const f32x4 xk = *(const f32x4*)&sx4[p][k];   // broadcast
                        const f32x2 sv = y0*xk.x + y1*xk.y + y2*xk.z + (uu + adjp[k]);
                        f32x2 e;
                        e.x = exp2f(sv.x);
                        e.y = exp2f(sv.y);
                        sum += e;
                        A0 += e * xk.x;
                        A1 += e * xk.y;
                        A2 += e * xk.z;
                    }
                    f32x2 inv;
                    inv.x = __builtin_amdgcn_rcpf(sum.x);
                    inv.y = __builtin_amdgcn_rcpf(sum.y);
                    const f32x2 b0 = A0 * inv, b1 = A1 * inv, b2 = A2 * inv;

                    // exchange (intra-wave in-order DS; no barrier needed)
                    unsigned* sxbw = &sxb[wv][0];
                    {
                        uint2 w0, w1;
                        w0.x = pack2bf(b0.x, b1.x);
                        w0.y = pack2bf(b2.x, 0.f);
                        w1.x = pack2bf(b0.y, b1.y);
                        w1.y = pack2bf(b2.y, 0.f);
                        *(uint2*)&sxbw[j0 * 20 + 2 * h]       = w0;
                        *(uint2*)&sxbw[(j0 + 8) * 20 + 2 * h] = w1;
                    }
                    const bf16x8 bvec = *(const bf16x8*)&sxbw[jB * 20 + lkB * 4];

                    // MFMA -> swizzled staging buffer (handoff to store wave)
                    float* sb = &sout[r & 1][wv][0];
                    __builtin_amdgcn_s_setprio(1);
#pragma unroll
                    for (int ct = 0; ct < 8; ++ct) {
                        f32x4 acc = *(const f32x4*)&sbp[ct * 16 + lkB * 4];
                        acc = __builtin_amdgcn_mfma_f32_16x16x32_bf16(ga[ct], bvec, acc, 0, 0, 0);
                        *(f32x4*)&sb[jB * 128 + (((ct * 4 + lkB) ^ (jB & 7)) << 2)] = acc;
                    }
                    __builtin_amdgcn_s_setprio(0);
                }
            }
        } else {
            // ================= STORE WAVE =================
            if (r >= 1) {
                const int p = (r - 1) * NW_C + (wv - NW_C);
                if (base + p < npos) {
                    const float* sb = &sout[(r - 1) & 1][wv - NW_C][0];
                    float* ob = out + (base + p) * (long)(NJ * DM);
#pragma unroll
                    for (int c2 = 0; c2 < 8; ++c2) {
                        const int jR = c2 * 2 + (l >> 5);
                        const int ul = l & 31;
                        const f32x4 vq = *(const f32x4*)&sb[jR * 128 + ((ul ^ (jR & 7)) << 2)];
                        *(f32x4*)(ob + c2 * 256 + l * 4) = vq;
                    }
                }
            }
        }
        __syncthreads();   // publishes sout[r&1]; frees sout[(r-1)&1]
    }
}

extern "C" void kernel_launch(void* const* d_in, const int* in_sizes, int n_in,
                              void* d_out, int out_size, void* d_ws, size_t ws_size,
                              hipStream_t stream) {
    const float* x  = (const float*)d_in[0];
    const float* Wq = (const float*)d_in[1];
    const float* bq = (const float*)d_in[2];
    const float* Wk = (const float*)d_in[3];
    const float* bk = (const float*)d_in[4];
    const float* Wv = (const float*)d_in[5];
    const float* bv = (const float*)d_in[6];
    const float* Wo = (const float*)d_in[7];
    const float* bo = (const float*)d_in[8];
    float* out    = (float*)d_out;
    unsigned* wsu = (unsigned*)d_ws;

    const int npos = in_sizes[0] / (NJ * 3);   // B*S
    skel_setup_kernel<<<9, 256, 0, stream>>>(Wq, bq, Wk, bk, Wv, bv, Wo, bo, wsu);
    const int grid = (npos + PPB - 1) / PPB;
    skel_main_kernel<<<grid, 512, 0, stream>>>(x, wsu, out, npos);
}

// Round 18
// 63.490 us; speedup vs baseline: 1.0819x; 1.0819x over previous
//
#include <hip/hip_runtime.h>

#define NJ   16
#define DM   128
#define NH   8
#define P    16         // positions per block (4 waves x 4 positions)
#define CL   0.36067376022224085f   // 0.25 * log2(e): folds score scale + exp->exp2

typedef __attribute__((ext_vector_type(8))) short bf16x8;
typedef __attribute__((ext_vector_type(4))) float f32x4;

// Kinematic adjacency (compile-time constant of the reference), UNscaled.
__constant__ float c_adj[NJ * NJ] = {
    1,1,0,0, 1,0,0,1, 0,0,1,0, 0,1,0,0,
    1,1,1,0, 0,0,0,0, 0,0,0,0, 0,0,0,0,
    0,1,1,1, 0,0,0,0, 0,0,0,0, 0,0,0,0,
    0,0,1,1, 0,0,0,0, 0,0,0,0, 0,0,0,0,
    1,0,0,0, 1,1,0,0.8f, 0,0,0,0, 0,0,0,0,
    0,0,0,0, 1,1,1,0, 0.8f,0,0,0, 0,0,0,0,
    0,0,0,0, 0,1,1,0, 0,0.8f,0,0, 0,0,0,0,
    1,0,0,0, 0.8f,0,0,1, 1,0,0,0, 0,0,0,0,
    0,0,0,0, 0,0.8f,0,1, 1,1,0,0, 0,0,0,0,
    0,0,0,0, 0,0,0.8f,0, 1,1,0,0, 0,0,0,0,
    1,0,0,0, 0,0,0,0, 0,0,1,1, 0,0.8f,0,0,
    0,0,0,0, 0,0,0,0, 0,0,1,1, 1,0,0.8f,0,
    0,0,0,0, 0,0,0,0, 0,0,0,1, 1,0,0,0.8f,
    1,0,0,0, 0,0,0,0, 0,0,0.8f,0, 0,1,1,0,
    0,0,0,0, 0,0,0,0, 0,0,0,0.8f, 0,1,1,1,
    0,0,0,0, 0,0,0,0, 0,0,0,0, 0.8f,0,1,1
};

// ws layout (32-bit words):
//   [0,128)     bp[128] fp32        : bv @ Wo + bo
//   [128,256)   pack[8][16] fp32    : per head: M*CL(9), a*CL(3), c*CL(3), d*CL(1)
//   [256,2304)  Gfrag[8][64][4] u32 : bf16x2-packed fragments, k = 4h+r (r==3 -> 0)
#define WS_BP_W   0
#define WS_PACK_W 128
#define WS_GF_W   256

__device__ __forceinline__ unsigned short f2bf(float f) {
    union { float f; unsigned u; } v; v.f = f;
    unsigned u = v.u;
    u += 0x7FFFu + ((u >> 16) & 1u);          // RNE
    return (unsigned short)(u >> 16);
}
__device__ __forceinline__ unsigned pack2bf(float lo, float hi) {
    return (unsigned)f2bf(lo) | ((unsigned)f2bf(hi) << 16);
}

__global__ __launch_bounds__(256) void skel_setup_kernel(
    const float* __restrict__ Wq, const float* __restrict__ bq,
    const float* __restrict__ Wk, const float* __restrict__ bk,
    const float* __restrict__ Wv, const float* __restrict__ bv,
    const float* __restrict__ Wo, const float* __restrict__ bo,
    unsigned* __restrict__ wsu)
{
    const int b = blockIdx.x, t = threadIdx.x;
    float* wsf = (float*)wsu;

    if (b < 8) {
        // One packed u32 (2 bf16, k-pair) of Gfrag per thread.
        const int idx = b * 256 + t;          // 0..2047
        const int ctl = idx >> 2, i = idx & 3;
        const int ct = ctl >> 6, l = ctl & 63;
        const int n  = ct * 16 + (l & 15);
        const int kb = (l >> 4) * 8;
        float v[2];
#pragma unroll
        for (int s = 0; s < 2; ++s) {
            const int k = kb + 2 * i + s;
            const int h = k >> 2, r = k & 3;
            float acc = 0.f;
            if (r < 3) {
#pragma unroll
                for (int dh = 0; dh < 16; ++dh)
                    acc += Wv[r * DM + h * 16 + dh] * Wo[(h * 16 + dh) * DM + n];
            }
            v[s] = acc;
        }
        wsu[WS_GF_W + idx] = pack2bf(v[0], v[1]);
        return;
    }
    // block 8: bp and per-head packs (pre-scaled by CL)
    if (t < 128) {
        const int n = t;
        float bv_ = bo[n];
        for (int d = 0; d < DM; ++d) bv_ += bv[d] * Wo[d * DM + n];
        wsf[WS_BP_W + n] = bv_;
    } else if (t < 128 + NH) {
        const int h = t - 128;
        float* o = &wsf[WS_PACK_W + h * 16];
#pragma unroll
        for (int r = 0; r < 3; ++r)
#pragma unroll
            for (int c = 0; c < 3; ++c) {
                float acc = 0.f;
#pragma unroll
                for (int dh = 0; dh < 16; ++dh)
                    acc += Wq[r * DM + h * 16 + dh] * Wk[c * DM + h * 16 + dh];
                o[r * 3 + c] = acc * CL;
            }
#pragma unroll
        for (int r = 0; r < 3; ++r) {
            float aa = 0.f, cc = 0.f;
#pragma unroll
            for (int dh = 0; dh < 16; ++dh) {
                aa += Wq[r * DM + h * 16 + dh] * bk[h * 16 + dh];
                cc += Wk[r * DM + h * 16 + dh] * bq[h * 16 + dh];
            }
            o[9 + r]  = aa * CL;
            o[12 + r] = cc * CL;
        }
        float dd = 0.f;
#pragma unroll
        for (int dh = 0; dh < 16; ++dh) dd += bq[h * 16 + dh] * bk[h * 16 + dh];
        o[15] = dd * CL;
    }
}

__global__ __launch_bounds__(256) void skel_main_kernel(
    const float* __restrict__ x,
    const unsigned* __restrict__ wsu,
    float* __restrict__ out,
    int npos)
{
    const int t = threadIdx.x;
    const long pos0 = (long)blockIdx.x * P;
    const float* wsf = (const float*)wsu;

    __shared__ __align__(16) float    sx4[P][NJ][4];    // {x,y,z,0} per joint (4 KB)
    __shared__ float                  sc[128];          // per-head packs (scaled)
    __shared__ __align__(16) float    sbp[128];         // b'
    __shared__ __align__(16) float    sout[4][NJ * DM]; // store staging (32 KB)
    // sxb (XB fragment rows, 320 u32/wave) ALIASES the tail of sout[wv]:
    // safe because per-wave LDS ops are processed in order — sout store-reads
    // of position i issue before position i+1's sxb pack-writes, and the
    // bvec read precedes this position's sout writes.

    // ---- stage (one barrier total) -------------------------------------
    {
        const int p = t >> 4, j = t & 15;     // all 256 threads: one joint each
        const long pidx = pos0 + p;
        const long base = pidx * 48 + j * 3;
        const bool ok = pidx < npos;
        sx4[p][j][0] = ok ? x[base + 0] : 0.f;
        sx4[p][j][1] = ok ? x[base + 1] : 0.f;
        sx4[p][j][2] = ok ? x[base + 2] : 0.f;
        sx4[p][j][3] = 0.f;
    }
    if (t < 128) sc[t]        = wsf[WS_PACK_W + t];
    else         sbp[t - 128] = wsf[WS_BP_W + (t - 128)];
    // G fragments straight to registers (coalesced 1KB/instr, L2-resident)
    const int l = t & 63;
    bf16x8 ga[8];
#pragma unroll
    for (int ct = 0; ct < 8; ++ct)
        ga[ct] = *(const bf16x8*)&wsu[WS_GF_W + (ct * 64 + l) * 4];
    __syncthreads();   // the ONLY barrier

    // ---- wave-autonomous processing ------------------------------------
    const int wv = t >> 6;
    const int h  = l >> 3, j0 = l & 7;     // lane owns joints j0 and j0+8 of head h
    const int jB = l & 15, lkB = l >> 4;   // MFMA fragment ids

    float m[16];
#pragma unroll
    for (int i = 0; i < 16; ++i) m[i] = sc[h * 16 + i];
    float adj0[NJ], adj1[NJ];
#pragma unroll
    for (int k = 0; k < NJ; ++k) {
        adj0[k] = c_adj[j0 * NJ + k] * CL;
        adj1[k] = c_adj[(j0 + 8) * NJ + k] * CL;
    }

    float*    so   = &sout[wv][0];
    unsigned* sxbw = (unsigned*)&sout[wv][NJ * DM - 320];   // aliased tail (1280 B)

    for (int it = 0; it < 4; ++it) {
        const int p = wv * 4 + it;
        const f32x4 xa = *(const f32x4*)&sx4[p][j0];
        const f32x4 xb = *(const f32x4*)&sx4[p][j0 + 8];

        // y_j = M^T x_j + c' ;  u_j = a'.x_j + d'
        const float y00 = m[0]*xa.x + m[3]*xa.y + m[6]*xa.z + m[12];
        const float y01 = m[1]*xa.x + m[4]*xa.y + m[7]*xa.z + m[13];
        const float y02 = m[2]*xa.x + m[5]*xa.y + m[8]*xa.z + m[14];
        const float u0  = m[9]*xa.x + m[10]*xa.y + m[11]*xa.z + m[15];
        const float y10 = m[0]*xb.x + m[3]*xb.y + m[6]*xb.z + m[12];
        const float y11 = m[1]*xb.x + m[4]*xb.y + m[7]*xb.z + m[13];
        const float y12 = m[2]*xb.x + m[5]*xb.y + m[8]*xb.z + m[14];
        const float u1  = m[9]*xb.x + m[10]*xb.y + m[11]*xb.z + m[15];

        float sum0 = 0.f, sum1 = 0.f;
        float a00 = 0.f, a01 = 0.f, a02 = 0.f;
        float a10 = 0.f, a11 = 0.f, a12 = 0.f;
#pragma unroll
        for (int k = 0; k < NJ; ++k) {
            const f32x4 xk = *(const f32x4*)&sx4[p][k];   // broadcast read
            const float e0 = exp2f(y00*xk.x + y01*xk.y + y02*xk.z + (u0 + adj0[k]));
            const float e1 = exp2f(y10*xk.x + y11*xk.y + y12*xk.z + (u1 + adj1[k]));
            sum0 += e0; sum1 += e1;
            a00 += e0 * xk.x; a01 += e0 * xk.y; a02 += e0 * xk.z;
            a10 += e1 * xk.x; a11 += e1 * xk.y; a12 += e1 * xk.z;
        }
        const float inv0 = __builtin_amdgcn_rcpf(sum0);
        const float inv1 = __builtin_amdgcn_rcpf(sum1);

        // pack XB fragment rows (k = 4h+r, r==3 -> 0); row stride 20 u32
        {
            uint2 w0, w1;
            w0.x = pack2bf(a00 * inv0, a01 * inv0);
            w0.y = pack2bf(a02 * inv0, 0.f);
            w1.x = pack2bf(a10 * inv1, a11 * inv1);
            w1.y = pack2bf(a12 * inv1, 0.f);
            *(uint2*)&sxbw[j0 * 20 + 2 * h]       = w0;
            *(uint2*)&sxbw[(j0 + 8) * 20 + 2 * h] = w1;
        }
        // intra-wave ds_write -> ds_read (compiler lgkmcnt; no barrier)
        const bf16x8 bvec = *(const bf16x8*)&sxbw[jB * 20 + lkB * 4];

        // ---- MFMA -> swizzled LDS staging (setprio: favor MFMA cluster) -
        __builtin_amdgcn_s_setprio(1);
#pragma unroll
        for (int ct = 0; ct < 8; ++ct) {
            f32x4 acc = *(const f32x4*)&sbp[ct * 16 + lkB * 4];
            acc = __builtin_amdgcn_mfma_f32_16x16x32_bf16(ga[ct], bvec, acc, 0, 0, 0);
            *(f32x4*)&so[jB * 128 + (((ct * 4 + lkB) ^ (jB & 7)) << 2)] = acc;
        }
        __builtin_amdgcn_s_setprio(0);

        // ---- fully-coalesced stores: 8 x 1024B-contiguous ---------------
        if (pos0 + p < npos) {
            float* ob = out + (pos0 + p) * (long)(NJ * DM);
#pragma unroll
            for (int c2 = 0; c2 < 8; ++c2) {
                const int jR = c2 * 2 + (l >> 5);
                const int ul = l & 31;
                const f32x4 vq = *(const f32x4*)&so[jR * 128 + ((ul ^ (jR & 7)) << 2)];
                *(f32x4*)(ob + c2 * 256 + l * 4) = vq;
            }
        }
    }
}

extern "C" void kernel_launch(void* const* d_in, const int* in_sizes, int n_in,
                              void* d_out, int out_size, void* d_ws, size_t ws_size,
                              hipStream_t stream) {
    const float* x  = (const float*)d_in[0];
    const float* Wq = (const float*)d_in[1];
    const float* bq = (const float*)d_in[2];
    const float* Wk = (const float*)d_in[3];
    const float* bk = (const float*)d_in[4];
    const float* Wv = (const float*)d_in[5];
    const float* bv = (const float*)d_in[6];
    const float* Wo = (const float*)d_in[7];
    const float* bo = (const float*)d_in[8];
    float* out    = (float*)d_out;
    unsigned* wsu = (unsigned*)d_ws;

    const int npos = in_sizes[0] / (NJ * 3);   // B*S
    skel_setup_kernel<<<9, 256, 0, stream>>>(Wq, bq, Wk, bk, Wv, bv, Wo, bo, wsu);
    const int grid = (npos + P - 1) / P;
    skel_main_kernel<<<grid, 256, 0, stream>>>(x, wsu, out, npos);
}